// Round 19
// baseline (191.865 us; speedup 1.0000x reference)
//
#include <hip/hip_runtime.h>

// Efficient (linear) attention, fused MFMA implementation for gfx950.  v14-r18
// (r17 resubmission; infra died before compile.)
// B=4, NX=NY=16384, C=256, H=8, dk=dv=32.  M = B*N = 65536 rows.
// R12 change: co-dispatch kv || qsm (independent work) in one 4096-block
// kernel; qout split into qsm (stage+qGEMM+softmax -> qsm buffer, pre-swizzled
// A-layout) and out2 (qsm -> GEMM2 vs M_b -> out). Needs ~107MB ws; guarded by
// ws_size with exact-v13 fallback (fused kernel runs as pure kv + mono qout).

typedef float f32x4 __attribute__((ext_vector_type(4)));
typedef short s16x4 __attribute__((ext_vector_type(4)));
typedef short s16x8 __attribute__((ext_vector_type(8)));

#define MFMA16(A, B, C) __builtin_amdgcn_mfma_f32_16x16x32_bf16((A), (B), (C), 0, 0, 0)

__device__ __forceinline__ short f2bf(float f) {
    __bf16 h = (__bf16)f;
    return __builtin_bit_cast(short, h);
}
__device__ __forceinline__ float bf2f(short b) {
    unsigned u = ((unsigned)(unsigned short)b) << 16;
    return __builtin_bit_cast(float, u);
}
__device__ __forceinline__ f32x4 ntld4f(const float* p) {
    return __builtin_nontemporal_load((const f32x4*)p);
}
__device__ __forceinline__ s16x8 ntld8s(const short* p) {
    return __builtin_nontemporal_load((const s16x8*)p);
}
__device__ __forceinline__ void ntst8s(short* p, s16x8 v) {
    __builtin_nontemporal_store(v, (s16x8*)p);
}
__device__ __forceinline__ void ntst4f(float* p, f32x4 v) {
    __builtin_nontemporal_store(v, (f32x4*)p);
}

// ---------------------------------------------------------------------------
// K0: weights -> bf16, MFMA-fragment-packed.
// ---------------------------------------------------------------------------
__global__ __launch_bounds__(256) void wcvt_kernel(
    const float* __restrict__ wq, const float* __restrict__ wk,
    const float* __restrict__ wv, const float* __restrict__ wr,
    short* __restrict__ wbf)
{
    int id = blockIdx.x * 256 + threadIdx.x;
    int m = id >> 13;
    int slot = id & 8191;
    int tile = slot >> 9;
    int ks   = (slot >> 6) & 7;
    int lane = slot & 63;
    int lrow = lane & 15, lgrp = lane >> 4;
    const float* src = (m == 0) ? wq : (m == 1) ? wk : (m == 2) ? wv : wr;
    const float* p = src + (size_t)(tile * 16 + lrow) * 256 + ks * 32 + lgrp * 8;
    f32x4 a = *(const f32x4*)p;
    f32x4 b = *(const f32x4*)(p + 4);
    s16x8 o;
    o[0]=f2bf(a[0]); o[1]=f2bf(a[1]); o[2]=f2bf(a[2]); o[3]=f2bf(a[3]);
    o[4]=f2bf(b[0]); o[5]=f2bf(b[1]); o[6]=f2bf(b[2]); o[7]=f2bf(b[3]);
    *(s16x8*)(wbf + (size_t)id * 8) = o;
}

// ---------------------------------------------------------------------------
// K1: fused kv || qsm.  blockIdx < qsm_base: kv tile; else qsm tile.
// ---------------------------------------------------------------------------
__global__ __launch_bounds__(256) void fused_kernel(
    const float* __restrict__ y, const float* __restrict__ ypos,
    const short* __restrict__ wkp, const short* __restrict__ wvp,
    const float* __restrict__ bk, const float* __restrict__ bv,
    short* __restrict__ e_buf, short* __restrict__ v_buf,
    const float* __restrict__ x, const float* __restrict__ xpos,
    const short* __restrict__ wqp, const float* __restrict__ bq,
    short* __restrict__ qsm, int qsm_base)
{
    __shared__ short smem[32 * 512];             // 32KB
    const int t = threadIdx.x;
    const int w = t >> 6, lane = t & 63;
    const int lrow = lane & 15, lgrp = lane >> 4;

    if ((int)blockIdx.x < qsm_base) {
        // ---------------- kv half (v13 verbatim) ----------------
        short* ak = smem;
        short* av = smem + 32 * 256;
        const int row0 = blockIdx.x * 32;

        #pragma unroll
        for (int it = 0; it < 8; ++it) {
            int r = it * 4 + w;
            f32x4 a = ntld4f(y    + (size_t)(row0 + r) * 256 + lane * 4);
            f32x4 p = ntld4f(ypos + (size_t)(row0 + r) * 256 + lane * 4);
            f32x4 k = a + p;
            s16x4 ov, ok;
            ov[0]=f2bf(a[0]); ov[1]=f2bf(a[1]); ov[2]=f2bf(a[2]); ov[3]=f2bf(a[3]);
            ok[0]=f2bf(k[0]); ok[1]=f2bf(k[1]); ok[2]=f2bf(k[2]); ok[3]=f2bf(k[3]);
            int swz = ((lane >> 1) ^ (r & 7)) * 8 + (lane & 1) * 4;
            *(s16x4*)(av + r * 256 + swz) = ov;
            *(s16x4*)(ak + r * 256 + swz) = ok;
        }
        __syncthreads();

        const bool is_k = (w < 2);
        const int colbase = (w & 1) * 128;
        const int tile0 = colbase >> 4;
        const short* WP = is_k ? wkp : wvp;
        const float* bp = is_k ? bk : bv;
        const short* A = is_k ? ak : av;

        float bias[8];
        #pragma unroll
        for (int nf = 0; nf < 8; ++nf) bias[nf] = bp[colbase + nf * 16 + lrow];

        s16x8 af[2][8];
        #pragma unroll
        for (int mf = 0; mf < 2; ++mf) {
            int rr = mf * 16 + lrow;
            #pragma unroll
            for (int ks = 0; ks < 8; ++ks) {
                int cs = ((ks * 4 + lgrp) ^ (rr & 7));
                af[mf][ks] = *(const s16x8*)(A + rr * 256 + cs * 8);
            }
        }
        __syncthreads();

        #pragma unroll
        for (int nf = 0; nf < 8; ++nf) {
            const int tile = tile0 + nf;
            const short* wt = WP + ((size_t)tile * 8) * 512 + lane * 8;
            f32x4 a0 = (f32x4){0.f, 0.f, 0.f, 0.f};
            f32x4 a1 = (f32x4){0.f, 0.f, 0.f, 0.f};
            #pragma unroll
            for (int kg = 0; kg < 2; ++kg) {
                s16x8 bf[4];
                #pragma unroll
                for (int kk = 0; kk < 4; ++kk)
                    bf[kk] = *(const s16x8*)(wt + (kg * 4 + kk) * 512);
                #pragma unroll
                for (int kk = 0; kk < 4; ++kk) {
                    a0 = MFMA16(af[0][kg * 4 + kk], bf[kk], a0);
                    a1 = MFMA16(af[1][kg * 4 + kk], bf[kk], a1);
                }
            }
            const int colp = (is_k ? 0 : 256) + colbase + nf * 16 + lrow;
            #pragma unroll
            for (int rr = 0; rr < 4; ++rr) {
                float v0 = a0[rr] + bias[nf];
                float v1 = a1[rr] + bias[nf];
                if (is_k) { v0 = __expf(v0); v1 = __expf(v1); }
                int lr0 = lgrp * 4 + rr;
                int lr1 = lr0 + 16;
                smem[lr0 * 512 + (((colp >> 3) ^ (lr0 & 7)) * 8) + (colp & 7)] = f2bf(v0);
                smem[lr1 * 512 + (((colp >> 3) ^ (lr1 & 7)) * 8) + (colp & 7)] = f2bf(v1);
            }
        }
        __syncthreads();

        #pragma unroll
        for (int i = 0; i < 8; ++i) {
            int r = i * 4 + w;
            int grow = row0 + r;
            s16x8 val = *(const s16x8*)(smem + r * 512 + ((lane ^ (r & 7)) << 3));
            if (lane < 32)
                ntst8s(e_buf + (size_t)grow * 256 + lane * 8, val);
            else
                ntst8s(v_buf + (size_t)grow * 256 + (lane - 32) * 8, val);
        }
    } else {
        // ---------------- qsm half ----------------
        short* alds = smem;                      // [32][256]
        const int blk = blockIdx.x - qsm_base;
        const int row0 = blk * 32;

        {
            f32x4 lx[8], lp[8];
            #pragma unroll
            for (int it = 0; it < 8; ++it) {
                int r = it * 4 + w;
                lx[it] = ntld4f(x    + (size_t)(row0 + r) * 256 + lane * 4);
                lp[it] = ntld4f(xpos + (size_t)(row0 + r) * 256 + lane * 4);
            }
            #pragma unroll
            for (int it = 0; it < 8; ++it) {
                int r = it * 4 + w;
                f32x4 a = lx[it] + lp[it];
                s16x4 o;
                o[0]=f2bf(a[0]); o[1]=f2bf(a[1]); o[2]=f2bf(a[2]); o[3]=f2bf(a[3]);
                int swz = ((lane >> 1) ^ (r & 7)) * 8 + (lane & 1) * 4;
                *(s16x4*)(alds + r * 256 + swz) = o;
            }
        }
        __syncthreads();

        const int wc = w * 64;
        const int tile0 = wc >> 4;

        float biasq[4];
        #pragma unroll
        for (int nf = 0; nf < 4; ++nf) biasq[nf] = bq[wc + nf * 16 + lrow];

        f32x4 acc[2][4];
        #pragma unroll
        for (int mf = 0; mf < 2; ++mf)
            #pragma unroll
            for (int nf = 0; nf < 4; ++nf) acc[mf][nf] = (f32x4){0.f, 0.f, 0.f, 0.f};

        {
            const short* wq8 = wqp + lane * 8;
            s16x8 bfq[2][4];
            #pragma unroll
            for (int nf = 0; nf < 4; ++nf)
                bfq[0][nf] = *(const s16x8*)(wq8 + ((size_t)(tile0 + nf) * 8 + 0) * 512);
            #pragma unroll
            for (int ks = 0; ks < 8; ++ks) {
                const int cur = ks & 1, nxt = cur ^ 1;
                if (ks < 7) {
                    #pragma unroll
                    for (int nf = 0; nf < 4; ++nf)
                        bfq[nxt][nf] = *(const s16x8*)(wq8 + ((size_t)(tile0 + nf) * 8 + ks + 1) * 512);
                }
                s16x8 af[2];
                #pragma unroll
                for (int mf = 0; mf < 2; ++mf) {
                    int rr = mf * 16 + lrow;
                    int cs = (ks * 4 + lgrp) ^ (rr & 7);
                    af[mf] = *(const s16x8*)(alds + rr * 256 + cs * 8);
                }
                #pragma unroll
                for (int nf = 0; nf < 4; ++nf) {
                    acc[0][nf] = MFMA16(af[0], bfq[cur][nf], acc[0][nf]);
                    acc[1][nf] = MFMA16(af[1], bfq[cur][nf], acc[1][nf]);
                }
            }
        }
        __syncthreads();

        // softmax -> alds (A-layout swizzled)
        #pragma unroll
        for (int mf = 0; mf < 2; ++mf) {
            f32x4 e[4];
            #pragma unroll
            for (int nf = 0; nf < 4; ++nf)
                #pragma unroll
                for (int rr = 0; rr < 4; ++rr)
                    e[nf][rr] = __expf(acc[mf][nf][rr] + biasq[nf]);
            #pragma unroll
            for (int hl = 0; hl < 2; ++hl) {
                #pragma unroll
                for (int rr = 0; rr < 4; ++rr) {
                    float s = e[hl * 2][rr] + e[hl * 2 + 1][rr];
                    s += __shfl_xor(s, 1);
                    s += __shfl_xor(s, 2);
                    s += __shfl_xor(s, 4);
                    s += __shfl_xor(s, 8);
                    float rinv = 1.0f / s;
                    int row = mf * 16 + lgrp * 4 + rr;
                    #pragma unroll
                    for (int n2 = 0; n2 < 2; ++n2) {
                        int col = wc + hl * 32 + n2 * 16 + lrow;
                        int cs = (col >> 3) ^ (row & 7);
                        alds[row * 256 + cs * 8 + (col & 7)] = f2bf(e[hl * 2 + n2][rr] * rinv);
                    }
                }
            }
        }
        __syncthreads();

        // linear copy of the alds image -> qsm (coalesced nt stores)
        short* qb = qsm + (size_t)blk * 8192;
        #pragma unroll
        for (int i = 0; i < 4; ++i) {
            s16x8 v = *(const s16x8*)(smem + i * 2048 + t * 8);
            ntst8s(qb + i * 2048 + t * 8, v);
        }
    }
}

// ---------------------------------------------------------------------------
// K2: ctx partials.  grid (32 chunks x 512 toks, 32 bh).  (v13)
// ---------------------------------------------------------------------------
__global__ __launch_bounds__(256) void ctx_kernel(
    const short* __restrict__ e_buf, const short* __restrict__ v_buf,
    float* __restrict__ partials)
{
    __shared__ float se[128 * 32];
    __shared__ float sv[128 * 32];
    __shared__ float red[4 * 1056];
    const int cb = blockIdx.x, bh = blockIdx.y;
    const int b = bh >> 3, h = bh & 7;
    const int tok0 = b * 16384 + cb * 512;
    const int t = threadIdx.x, w = t >> 6, lane = t & 63;
    const int ckb = (lane >> 3) * 4, cvb = (lane & 7) * 4;

    f32x4 acc[4];
    #pragma unroll
    for (int i = 0; i < 4; ++i) acc[i] = (f32x4){0.f, 0.f, 0.f, 0.f};
    f32x4 dn = (f32x4){0.f, 0.f, 0.f, 0.f};

    for (int it = 0; it < 4; ++it) {
        __syncthreads();
        #pragma unroll
        for (int s = 0; s < 2; ++s) {
            int id = t + s * 256;
            int rr = id >> 2, pp = id & 3;
            size_t g = (size_t)(tok0 + it * 128 + rr) * 256 + h * 32 + pp * 8;
            s16x8 ee = ntld8s(e_buf + g);
            s16x8 vv = ntld8s(v_buf + g);
            f32x4 e0 = {bf2f(ee[0]), bf2f(ee[1]), bf2f(ee[2]), bf2f(ee[3])};
            f32x4 e1 = {bf2f(ee[4]), bf2f(ee[5]), bf2f(ee[6]), bf2f(ee[7])};
            f32x4 v0 = {bf2f(vv[0]), bf2f(vv[1]), bf2f(vv[2]), bf2f(vv[3])};
            f32x4 v1 = {bf2f(vv[4]), bf2f(vv[5]), bf2f(vv[6]), bf2f(vv[7])};
            *(f32x4*)(se + rr * 32 + pp * 8)     = e0;
            *(f32x4*)(se + rr * 32 + pp * 8 + 4) = e1;
            *(f32x4*)(sv + rr * 32 + pp * 8)     = v0;
            *(f32x4*)(sv + rr * 32 + pp * 8 + 4) = v1;
        }
        __syncthreads();
        const int r0 = w * 32;
        #pragma unroll 8
        for (int rr = 0; rr < 32; ++rr) {
            f32x4 e4 = *(const f32x4*)(se + (r0 + rr) * 32 + ckb);
            f32x4 v4 = *(const f32x4*)(sv + (r0 + rr) * 32 + cvb);
            acc[0] += e4[0] * v4;
            acc[1] += e4[1] * v4;
            acc[2] += e4[2] * v4;
            acc[3] += e4[3] * v4;
            dn += e4;
        }
    }
    __syncthreads();
    #pragma unroll
    for (int i = 0; i < 4; ++i)
        *(f32x4*)(red + w * 1056 + (ckb + i) * 32 + cvb) = acc[i];
    if ((lane & 7) == 0)
        *(f32x4*)(red + w * 1056 + 1024 + ckb) = dn;
    __syncthreads();
    float* outp = partials + (size_t)(bh * 32 + cb) * 1056;
    for (int e = t; e < 1056; e += 256)
        outp[e] = red[e] + red[1056 + e] + red[2112 + e] + red[3168 + e];
}

// ---------------------------------------------------------------------------
// K2b: reduce 32 chunks, normalize, fold Wr -> M_b packed.  (v13)
// ---------------------------------------------------------------------------
__global__ __launch_bounds__(256) void ctxred2_kernel(
    const float* __restrict__ partials, const float* __restrict__ wr,
    short* __restrict__ mpk)
{
    __shared__ float s[1056];
    const int bh = blockIdx.x, t = threadIdx.x;
    const int b = bh >> 3, h = bh & 7;
    for (int e = t; e < 1056; e += 256) {
        float a = 0.f;
        #pragma unroll 4
        for (int c = 0; c < 32; ++c) a += partials[(size_t)(bh * 32 + c) * 1056 + e];
        s[e] = a;
    }
    __syncthreads();
    for (int e = t; e < 1024; e += 256)
        s[e] = s[e] / s[1024 + (e >> 5)];
    __syncthreads();

    #pragma unroll 4
    for (int i = 0; i < 32; ++i) {
        int linear = i * 256 + t;
        int tile = linear >> 9, rem = linear & 511;
        int lane = rem >> 3, j = rem & 7;
        int col = tile * 16 + (lane & 15);
        int ck = (lane >> 4) * 8 + j;
        const float* wrow = wr + (size_t)col * 256 + h * 32;
        const float* cr = s + ck * 32;
        float m = 0.f;
        #pragma unroll
        for (int dv = 0; dv < 32; dv += 4) {
            f32x4 wv = *(const f32x4*)(wrow + dv);
            m += cr[dv] * wv[0] + cr[dv + 1] * wv[1]
               + cr[dv + 2] * wv[2] + cr[dv + 3] * wv[3];
        }
        mpk[(((size_t)(b * 16 + tile)) * 8 + h) * 512 + rem] = f2bf(m);
    }
}

// ---------------------------------------------------------------------------
// K3a (fused path): out2 = qsm @ M_b + br -> fp32 out.  grid 2048.
// ---------------------------------------------------------------------------
__global__ __launch_bounds__(256) void out2_kernel(
    const short* __restrict__ qsm, const short* __restrict__ mpk,
    const float* __restrict__ br, float* __restrict__ out)
{
    __shared__ short smem[32 * 512];             // alds 16KB then cf 32KB
    short* alds = smem;
    const int row0 = blockIdx.x * 32;
    const int b = row0 >> 14;
    const int t = threadIdx.x;
    const int w = t >> 6, lane = t & 63;
    const int lrow = lane & 15, lgrp = lane >> 4;
    const int wc = w * 64;
    const int tile0 = wc >> 4;

    { // linear staged copy of the alds image
        const short* qb = qsm + (size_t)blockIdx.x * 8192;
        #pragma unroll
        for (int i = 0; i < 4; ++i) {
            s16x8 v = ntld8s(qb + i * 2048 + t * 8);
            *(s16x8*)(smem + i * 2048 + t * 8) = v;
        }
    }
    __syncthreads();

    float biasr[4];
    #pragma unroll
    for (int nf = 0; nf < 4; ++nf) biasr[nf] = br[wc + nf * 16 + lrow];

    f32x4 acc2[2][4];
    #pragma unroll
    for (int mf = 0; mf < 2; ++mf)
        #pragma unroll
        for (int nf = 0; nf < 4; ++nf) acc2[mf][nf] = (f32x4){0.f, 0.f, 0.f, 0.f};

    {
        const short* mp8 = mpk + (size_t)b * 65536 + lane * 8;
        s16x8 bfr[2][4];
        #pragma unroll
        for (int nf = 0; nf < 4; ++nf)
            bfr[0][nf] = *(const s16x8*)(mp8 + ((size_t)(tile0 + nf) * 8 + 0) * 512);
        #pragma unroll
        for (int ks = 0; ks < 8; ++ks) {
            const int cur = ks & 1, nxt = cur ^ 1;
            if (ks < 7) {
                #pragma unroll
                for (int nf = 0; nf < 4; ++nf)
                    bfr[nxt][nf] = *(const s16x8*)(mp8 + ((size_t)(tile0 + nf) * 8 + ks + 1) * 512);
            }
            s16x8 af[2];
            #pragma unroll
            for (int mf = 0; mf < 2; ++mf) {
                int rr = mf * 16 + lrow;
                int cs = (ks * 4 + lgrp) ^ (rr & 7);
                af[mf] = *(const s16x8*)(alds + rr * 256 + cs * 8);
            }
            #pragma unroll
            for (int nf = 0; nf < 4; ++nf) {
                acc2[0][nf] = MFMA16(af[0], bfr[cur][nf], acc2[0][nf]);
                acc2[1][nf] = MFMA16(af[1], bfr[cur][nf], acc2[1][nf]);
            }
        }
    }
    __syncthreads();

    float* cf = (float*)smem;
    #pragma unroll
    for (int mf = 0; mf < 2; ++mf)
      #pragma unroll
      for (int nf = 0; nf < 4; ++nf)
        #pragma unroll
        for (int rr = 0; rr < 4; ++rr) {
            int row = mf * 16 + lgrp * 4 + rr;
            int col = wc + nf * 16 + lrow;
            int chunk = col >> 2, pos = col & 3;
            cf[row * 256 + ((chunk ^ (row & 7)) << 2) + pos] = acc2[mf][nf][rr] + biasr[nf];
        }
    __syncthreads();

    #pragma unroll
    for (int i = 0; i < 8; ++i) {
        int r = i * 4 + w;
        f32x4 val = *(const f32x4*)(cf + r * 256 + (((lane ^ (r & 7)) & 63) << 2));
        ntst4f(out + (size_t)(row0 + r) * 256 + lane * 4, val);
    }
}

// ---------------------------------------------------------------------------
// K3b (fallback path): monolithic qout (v13 verbatim).
// ---------------------------------------------------------------------------
__global__ __launch_bounds__(256) void qout_kernel(
    const float* __restrict__ x, const float* __restrict__ xpos,
    const short* __restrict__ wqp, const float* __restrict__ bq,
    const short* __restrict__ mpk, const float* __restrict__ br,
    float* __restrict__ out)
{
    __shared__ short smem[32 * 512];
    short* alds = smem;
    const int row0 = blockIdx.x * 32;
    const int b = row0 >> 14;
    const int t = threadIdx.x;
    const int w = t >> 6, lane = t & 63;

    {
        f32x4 lx[8], lp[8];
        #pragma unroll
        for (int it = 0; it < 8; ++it) {
            int r = it * 4 + w;
            lx[it] = ntld4f(x    + (size_t)(row0 + r) * 256 + lane * 4);
            lp[it] = ntld4f(xpos + (size_t)(row0 + r) * 256 + lane * 4);
        }
        #pragma unroll
        for (int it = 0; it < 8; ++it) {
            int r = it * 4 + w;
            f32x4 a = lx[it] + lp[it];
            s16x4 o;
            o[0]=f2bf(a[0]); o[1]=f2bf(a[1]); o[2]=f2bf(a[2]); o[3]=f2bf(a[3]);
            int swz = ((lane >> 1) ^ (r & 7)) * 8 + (lane & 1) * 4;
            *(s16x4*)(alds + r * 256 + swz) = o;
        }
    }
    __syncthreads();

    const int lrow = lane & 15, lgrp = lane >> 4;
    const int wc = w * 64;
    const int tile0 = wc >> 4;

    float biasq[4];
    #pragma unroll
    for (int nf = 0; nf < 4; ++nf) biasq[nf] = bq[wc + nf * 16 + lrow];

    f32x4 acc[2][4];
    #pragma unroll
    for (int mf = 0; mf < 2; ++mf)
        #pragma unroll
        for (int nf = 0; nf < 4; ++nf) acc[mf][nf] = (f32x4){0.f, 0.f, 0.f, 0.f};

    {
        const short* wq8 = wqp + lane * 8;
        s16x8 bfq[2][4];
        #pragma unroll
        for (int nf = 0; nf < 4; ++nf)
            bfq[0][nf] = *(const s16x8*)(wq8 + ((size_t)(tile0 + nf) * 8 + 0) * 512);
        #pragma unroll
        for (int ks = 0; ks < 8; ++ks) {
            const int cur = ks & 1, nxt = cur ^ 1;
            if (ks < 7) {
                #pragma unroll
                for (int nf = 0; nf < 4; ++nf)
                    bfq[nxt][nf] = *(const s16x8*)(wq8 + ((size_t)(tile0 + nf) * 8 + ks + 1) * 512);
            }
            s16x8 af[2];
            #pragma unroll
            for (int mf = 0; mf < 2; ++mf) {
                int rr = mf * 16 + lrow;
                int cs = (ks * 4 + lgrp) ^ (rr & 7);
                af[mf] = *(const s16x8*)(alds + rr * 256 + cs * 8);
            }
            #pragma unroll
            for (int nf = 0; nf < 4; ++nf) {
                acc[0][nf] = MFMA16(af[0], bfq[cur][nf], acc[0][nf]);
                acc[1][nf] = MFMA16(af[1], bfq[cur][nf], acc[1][nf]);
            }
        }
    }
    __syncthreads();

    #pragma unroll
    for (int mf = 0; mf < 2; ++mf) {
        f32x4 e[4];
        #pragma unroll
        for (int nf = 0; nf < 4; ++nf)
            #pragma unroll
            for (int rr = 0; rr < 4; ++rr)
                e[nf][rr] = __expf(acc[mf][nf][rr] + biasq[nf]);
        #pragma unroll
        for (int hl = 0; hl < 2; ++hl) {
            #pragma unroll
            for (int rr = 0; rr < 4; ++rr) {
                float s = e[hl * 2][rr] + e[hl * 2 + 1][rr];
                s += __shfl_xor(s, 1);
                s += __shfl_xor(s, 2);
                s += __shfl_xor(s, 4);
                s += __shfl_xor(s, 8);
                float rinv = 1.0f / s;
                int row = mf * 16 + lgrp * 4 + rr;
                #pragma unroll
                for (int n2 = 0; n2 < 2; ++n2) {
                    int col = wc + hl * 32 + n2 * 16 + lrow;
                    int cs = (col >> 3) ^ (row & 7);
                    alds[row * 256 + cs * 8 + (col & 7)] = f2bf(e[hl * 2 + n2][rr] * rinv);
                }
            }
        }
    }
    __syncthreads();

    float biasr[4];
    #pragma unroll
    for (int nf = 0; nf < 4; ++nf) biasr[nf] = br[wc + nf * 16 + lrow];

    f32x4 acc2[2][4];
    #pragma unroll
    for (int mf = 0; mf < 2; ++mf)
        #pragma unroll
        for (int nf = 0; nf < 4; ++nf) acc2[mf][nf] = (f32x4){0.f, 0.f, 0.f, 0.f};

    {
        const short* mp8 = mpk + (size_t)b * 65536 + lane * 8;
        s16x8 bfr[2][4];
        #pragma unroll
        for (int nf = 0; nf < 4; ++nf)
            bfr[0][nf] = *(const s16x8*)(mp8 + ((size_t)(tile0 + nf) * 8 + 0) * 512);
        #pragma unroll
        for (int ks = 0; ks < 8; ++ks) {
            const int cur = ks & 1, nxt = cur ^ 1;
            if (ks < 7) {
                #pragma unroll
                for (int nf = 0; nf < 4; ++nf)
                    bfr[nxt][nf] = *(const s16x8*)(mp8 + ((size_t)(tile0 + nf) * 8 + ks + 1) * 512);
            }
            s16x8 af[2];
            #pragma unroll
            for (int mf = 0; mf < 2; ++mf) {
                int rr = mf * 16 + lrow;
                int cs = (ks * 4 + lgrp) ^ (rr & 7);
                af[mf] = *(const s16x8*)(alds + rr * 256 + cs * 8);
            }
            #pragma unroll
            for (int nf = 0; nf < 4; ++nf) {
                acc2[0][nf] = MFMA16(af[0], bfr[cur][nf], acc2[0][nf]);
                acc2[1][nf] = MFMA16(af[1], bfr[cur][nf], acc2[1][nf]);
            }
        }
    }
    __syncthreads();

    float* cf = (float*)smem;
    #pragma unroll
    for (int mf = 0; mf < 2; ++mf)
      #pragma unroll
      for (int nf = 0; nf < 4; ++nf)
        #pragma unroll
        for (int rr = 0; rr < 4; ++rr) {
            int row = mf * 16 + lgrp * 4 + rr;
            int col = wc + nf * 16 + lrow;
            int chunk = col >> 2, pos = col & 3;
            cf[row * 256 + ((chunk ^ (row & 7)) << 2) + pos] = acc2[mf][nf][rr] + biasr[nf];
        }
    __syncthreads();

    #pragma unroll
    for (int i = 0; i < 8; ++i) {
        int r = i * 4 + w;
        f32x4 val = *(const f32x4*)(cf + r * 256 + (((lane ^ (r & 7)) & 63) << 2));
        ntst4f(out + (size_t)(row0 + r) * 256 + lane * 4, val);
    }
}

// ---------------------------------------------------------------------------
extern "C" void kernel_launch(void* const* d_in, const int* in_sizes, int n_in,
                              void* d_out, int out_size, void* d_ws, size_t ws_size,
                              hipStream_t stream)
{
    const float* x    = (const float*)d_in[0];
    const float* y    = (const float*)d_in[1];
    const float* xpos = (const float*)d_in[2];
    const float* ypos = (const float*)d_in[3];
    const float* Wq   = (const float*)d_in[4];
    const float* bq   = (const float*)d_in[5];
    const float* Wk   = (const float*)d_in[6];
    const float* bk   = (const float*)d_in[7];
    const float* Wv   = (const float*)d_in[8];
    const float* bv   = (const float*)d_in[9];
    const float* Wr   = (const float*)d_in[10];
    const float* br   = (const float*)d_in[11];

    char*  ws    = (char*)d_ws;
    short* wbf   = (short*)(ws);                     // 512 KB packed weights
    short* mpk   = (short*)(ws + 524288);            // 512 KB
    float* parts = (float*)(ws + (1 << 20));         // 4.33 MB
    short* e_buf = (short*)(ws + ((size_t)6 << 20)); // 33.5 MB
    short* v_buf = e_buf + (size_t)65536 * 256;      // 33.5 MB  (ends ~73 MB)
    short* qsm   = (short*)(ws + ((size_t)74 << 20)); // 33.5 MB (ends ~107.5 MB)
    float* outp  = (float*)d_out;

    const bool big_ws = ws_size >= ((size_t)112 << 20);

    hipLaunchKernelGGL(wcvt_kernel, dim3(128), dim3(256), 0, stream,
                       Wq, Wk, Wv, Wr, wbf);
    if (big_ws) {
        hipLaunchKernelGGL(fused_kernel, dim3(4096), dim3(256), 0, stream,
                           y, ypos, wbf + 65536, wbf + 131072, bk, bv, e_buf, v_buf,
                           x, xpos, wbf, bq, qsm, 2048);
        hipLaunchKernelGGL(ctx_kernel, dim3(32, 32), dim3(256), 0, stream,
                           e_buf, v_buf, parts);
        hipLaunchKernelGGL(ctxred2_kernel, dim3(32), dim3(256), 0, stream,
                           parts, Wr, mpk);
        hipLaunchKernelGGL(out2_kernel, dim3(2048), dim3(256), 0, stream,
                           qsm, mpk, br, outp);
    } else {
        hipLaunchKernelGGL(fused_kernel, dim3(2048), dim3(256), 0, stream,
                           y, ypos, wbf + 65536, wbf + 131072, bk, bv, e_buf, v_buf,
                           x, xpos, wbf, bq, (short*)e_buf /*unused*/, 2048);
        hipLaunchKernelGGL(ctx_kernel, dim3(32, 32), dim3(256), 0, stream,
                           e_buf, v_buf, parts);
        hipLaunchKernelGGL(ctxred2_kernel, dim3(32), dim3(256), 0, stream,
                           parts, Wr, mpk);
        hipLaunchKernelGGL(qout_kernel, dim3(2048), dim3(256), 0, stream,
                           x, xpos, wbf, bq, mpk, br, outp);
    }
}

// Round 20
// 158.551 us; speedup vs baseline: 1.2101x; 1.2101x over previous
//
#include <hip/hip_runtime.h>

// Efficient (linear) attention, fused MFMA implementation for gfx950.  v11-r19
// (Exact resubmission of v11-r14, the best measured config: 158.8 us.
//  R12/R13 experiments — attend-fold, ctx widening, kv||qsm co-dispatch —
//  all regressed the total and are reverted.)
// B=4, NX=NY=16384, C=256, H=8, dk=dv=32.  M = B*N = 65536 rows.

typedef float f32x4 __attribute__((ext_vector_type(4)));
typedef short s16x4 __attribute__((ext_vector_type(4)));
typedef short s16x8 __attribute__((ext_vector_type(8)));

#define MFMA16(A, B, C) __builtin_amdgcn_mfma_f32_16x16x32_bf16((A), (B), (C), 0, 0, 0)

__device__ __forceinline__ short f2bf(float f) {
    unsigned u = __builtin_bit_cast(unsigned, f);
    u = (u + 0x7FFFu + ((u >> 16) & 1u)) >> 16;   // RNE
    return (short)u;
}
__device__ __forceinline__ float bf2f(short b) {
    unsigned u = ((unsigned)(unsigned short)b) << 16;
    return __builtin_bit_cast(float, u);
}
__device__ __forceinline__ f32x4 ntld4f(const float* p) {
    return __builtin_nontemporal_load((const f32x4*)p);
}
__device__ __forceinline__ s16x8 ntld8s(const short* p) {
    return __builtin_nontemporal_load((const s16x8*)p);
}
__device__ __forceinline__ void ntst8s(short* p, s16x8 v) {
    __builtin_nontemporal_store(v, (s16x8*)p);
}
__device__ __forceinline__ void ntst4f(float* p, f32x4 v) {
    __builtin_nontemporal_store(v, (f32x4*)p);
}

// ---------------------------------------------------------------------------
// K0: convert 4 weight matrices to bf16 in MFMA-fragment-packed order.
// packed[m][tile][ks][lane][8] ; element = W[tile*16 + (lane&15)][ks*32 + (lane>>4)*8 + j]
// ---------------------------------------------------------------------------
__global__ __launch_bounds__(256) void wcvt_kernel(
    const float* __restrict__ wq, const float* __restrict__ wk,
    const float* __restrict__ wv, const float* __restrict__ wr,
    short* __restrict__ wbf)
{
    int id = blockIdx.x * 256 + threadIdx.x;     // grid 128 -> 32768 frag-slots
    int m = id >> 13;
    int slot = id & 8191;
    int tile = slot >> 9;
    int ks   = (slot >> 6) & 7;
    int lane = slot & 63;
    int lrow = lane & 15, lgrp = lane >> 4;
    const float* src = (m == 0) ? wq : (m == 1) ? wk : (m == 2) ? wv : wr;
    const float* p = src + (size_t)(tile * 16 + lrow) * 256 + ks * 32 + lgrp * 8;
    f32x4 a = *(const f32x4*)p;
    f32x4 b = *(const f32x4*)(p + 4);
    s16x8 o;
    o[0]=f2bf(a[0]); o[1]=f2bf(a[1]); o[2]=f2bf(a[2]); o[3]=f2bf(a[3]);
    o[4]=f2bf(b[0]); o[5]=f2bf(b[1]); o[6]=f2bf(b[2]); o[7]=f2bf(b[3]);
    *(s16x8*)(wbf + (size_t)id * 8) = o;
}

// ---------------------------------------------------------------------------
// K1: e = exp((y+ypos) @ Wk^T + bk), v = y @ Wv^T + bv   -> bf16 buffers
// v6-r9 form: 256 thr (4 waves), 32-row tile, grid 2048, 32KB LDS,
// LDS-bounced coalesced stores.  + nt loads/stores for streaming traffic.
// ---------------------------------------------------------------------------
__global__ __launch_bounds__(256, 4) void kv_kernel(
    const float* __restrict__ y, const float* __restrict__ ypos,
    const short* __restrict__ wkp, const short* __restrict__ wvp,
    const float* __restrict__ bk, const float* __restrict__ bv,
    short* __restrict__ e_buf, short* __restrict__ v_buf)
{
    __shared__ short smem[32 * 512];             // 32KB, dual-purpose
    short* ak = smem;                            // [32][256] swizzled bf16(y+ypos)
    short* av = smem + 32 * 256;                 // [32][256] swizzled bf16(y)
    const int row0 = blockIdx.x * 32;
    const int t = threadIdx.x;
    const int w = t >> 6, lane = t & 63;

    { // stage 32 rows; one full 1KB row per wave-instruction (nt loads)
        #pragma unroll
        for (int it = 0; it < 8; ++it) {
            int r = it * 4 + w;
            f32x4 a = ntld4f(y    + (size_t)(row0 + r) * 256 + lane * 4);
            f32x4 p = ntld4f(ypos + (size_t)(row0 + r) * 256 + lane * 4);
            f32x4 k = a + p;
            s16x4 ov, ok;
            ov[0]=f2bf(a[0]); ov[1]=f2bf(a[1]); ov[2]=f2bf(a[2]); ov[3]=f2bf(a[3]);
            ok[0]=f2bf(k[0]); ok[1]=f2bf(k[1]); ok[2]=f2bf(k[2]); ok[3]=f2bf(k[3]);
            int swz = ((lane >> 1) ^ (r & 7)) * 8 + (lane & 1) * 4;
            *(s16x4*)(av + r * 256 + swz) = ov;
            *(s16x4*)(ak + r * 256 + swz) = ok;
        }
    }
    __syncthreads();

    const int lrow = lane & 15, lgrp = lane >> 4;
    const bool is_k = (w < 2);                   // wave-uniform
    const int colbase = (w & 1) * 128;
    const int tile0 = colbase >> 4;
    const short* WP = is_k ? wkp : wvp;
    const float* bp = is_k ? bk : bv;
    const short* A = is_k ? ak : av;

    float bias[8];
    #pragma unroll
    for (int nf = 0; nf < 8; ++nf) bias[nf] = bp[colbase + nf * 16 + lrow];

    // A-frags from LDS into registers: af[mf][ks]
    s16x8 af[2][8];
    #pragma unroll
    for (int mf = 0; mf < 2; ++mf) {
        int rr = mf * 16 + lrow;
        #pragma unroll
        for (int ks = 0; ks < 8; ++ks) {
            int cs = ((ks * 4 + lgrp) ^ (rr & 7));
            af[mf][ks] = *(const s16x8*)(A + rr * 256 + cs * 8);
        }
    }
    __syncthreads();   // all waves have A in regs; smem reusable for C

    #pragma unroll
    for (int nf = 0; nf < 8; ++nf) {
        const int tile = tile0 + nf;
        const short* wt = WP + ((size_t)tile * 8) * 512 + lane * 8;
        f32x4 a0 = (f32x4){0.f, 0.f, 0.f, 0.f};
        f32x4 a1 = (f32x4){0.f, 0.f, 0.f, 0.f};
        #pragma unroll
        for (int kg = 0; kg < 2; ++kg) {         // batch B by 4
            s16x8 bf[4];
            #pragma unroll
            for (int kk = 0; kk < 4; ++kk)
                bf[kk] = *(const s16x8*)(wt + (kg * 4 + kk) * 512);
            #pragma unroll
            for (int kk = 0; kk < 4; ++kk) {
                a0 = MFMA16(af[0][kg * 4 + kk], bf[kk], a0);
                a1 = MFMA16(af[1][kg * 4 + kk], bf[kk], a1);
            }
        }
        // C -> LDS [32][512] bf16, 16B-chunk XOR swizzle
        const int colp = (is_k ? 0 : 256) + colbase + nf * 16 + lrow;
        #pragma unroll
        for (int rr = 0; rr < 4; ++rr) {
            float v0 = a0[rr] + bias[nf];
            float v1 = a1[rr] + bias[nf];
            if (is_k) { v0 = __expf(v0); v1 = __expf(v1); }
            int lr0 = lgrp * 4 + rr;
            int lr1 = lr0 + 16;
            smem[lr0 * 512 + (((colp >> 3) ^ (lr0 & 7)) * 8) + (colp & 7)] = f2bf(v0);
            smem[lr1 * 512 + (((colp >> 3) ^ (lr1 & 7)) * 8) + (colp & 7)] = f2bf(v1);
        }
    }
    __syncthreads();

    { // coalesced nt store-out
        #pragma unroll
        for (int i = 0; i < 8; ++i) {
            int r = i * 4 + w;
            int grow = row0 + r;
            s16x8 val = *(const s16x8*)(smem + r * 512 + ((lane ^ (r & 7)) << 3));
            if (lane < 32)
                ntst8s(e_buf + (size_t)grow * 256 + lane * 8, val);
            else
                ntst8s(v_buf + (size_t)grow * 256 + (lane - 32) * 8, val);
        }
    }
}

// ---------------------------------------------------------------------------
// K2: ctx partials.  grid (16 chunks, 32 bh).  block 256 thr.  (+nt loads)
// ---------------------------------------------------------------------------
__global__ __launch_bounds__(256) void ctx_kernel(
    const short* __restrict__ e_buf, const short* __restrict__ v_buf,
    float* __restrict__ partials)
{
    __shared__ float se[128 * 32];
    __shared__ float sv[128 * 32];
    __shared__ float red[4 * 1056];
    const int cb = blockIdx.x, bh = blockIdx.y;
    const int b = bh >> 3, h = bh & 7;
    const int tok0 = b * 16384 + cb * 1024;
    const int t = threadIdx.x, w = t >> 6, lane = t & 63;
    const int ckb = (lane >> 3) * 4, cvb = (lane & 7) * 4;

    f32x4 acc[4];
    #pragma unroll
    for (int i = 0; i < 4; ++i) acc[i] = (f32x4){0.f, 0.f, 0.f, 0.f};
    f32x4 dn = (f32x4){0.f, 0.f, 0.f, 0.f};

    for (int it = 0; it < 8; ++it) {
        __syncthreads();
        #pragma unroll
        for (int s = 0; s < 2; ++s) {
            int id = t + s * 256;
            int rr = id >> 2, pp = id & 3;
            size_t g = (size_t)(tok0 + it * 128 + rr) * 256 + h * 32 + pp * 8;
            s16x8 ee = ntld8s(e_buf + g);
            s16x8 vv = ntld8s(v_buf + g);
            f32x4 e0 = {bf2f(ee[0]), bf2f(ee[1]), bf2f(ee[2]), bf2f(ee[3])};
            f32x4 e1 = {bf2f(ee[4]), bf2f(ee[5]), bf2f(ee[6]), bf2f(ee[7])};
            f32x4 v0 = {bf2f(vv[0]), bf2f(vv[1]), bf2f(vv[2]), bf2f(vv[3])};
            f32x4 v1 = {bf2f(vv[4]), bf2f(vv[5]), bf2f(vv[6]), bf2f(vv[7])};
            *(f32x4*)(se + rr * 32 + pp * 8)     = e0;
            *(f32x4*)(se + rr * 32 + pp * 8 + 4) = e1;
            *(f32x4*)(sv + rr * 32 + pp * 8)     = v0;
            *(f32x4*)(sv + rr * 32 + pp * 8 + 4) = v1;
        }
        __syncthreads();
        const int r0 = w * 32;
        #pragma unroll 8
        for (int rr = 0; rr < 32; ++rr) {
            f32x4 e4 = *(const f32x4*)(se + (r0 + rr) * 32 + ckb);
            f32x4 v4 = *(const f32x4*)(sv + (r0 + rr) * 32 + cvb);
            acc[0] += e4[0] * v4;
            acc[1] += e4[1] * v4;
            acc[2] += e4[2] * v4;
            acc[3] += e4[3] * v4;
            dn += e4;
        }
    }
    __syncthreads();
    #pragma unroll
    for (int i = 0; i < 4; ++i)
        *(f32x4*)(red + w * 1056 + (ckb + i) * 32 + cvb) = acc[i];
    if ((lane & 7) == 0)
        *(f32x4*)(red + w * 1056 + 1024 + ckb) = dn;
    __syncthreads();
    float* outp = partials + (size_t)(bh * 16 + cb) * 1056;
    for (int e = t; e < 1056; e += 256)
        outp[e] = red[e] + red[1056 + e] + red[2112 + e] + red[3168 + e];
}

// K2b: reduce 16 chunks, normalize, write ctx^T bf16 [bh][cv][ck]
__global__ __launch_bounds__(256) void ctx_reduce_kernel(
    const float* __restrict__ partials, short* __restrict__ ctxT)
{
    __shared__ float s[1056];
    const int bh = blockIdx.x, t = threadIdx.x;
    for (int e = t; e < 1056; e += 256) {
        float a = 0.f;
        for (int c = 0; c < 16; ++c) a += partials[(size_t)(bh * 16 + c) * 1056 + e];
        s[e] = a;
    }
    __syncthreads();
    for (int e = t; e < 1024; e += 256) {
        int ck = e >> 5, cv = e & 31;
        float val = s[e] / s[1024 + ck];
        ctxT[(size_t)bh * 1024 + cv * 32 + ck] = f2bf(val);
    }
}

// ---------------------------------------------------------------------------
// K3: fused q pass.  256 thr, 32 rows, grid 2048.  v7 form (hoisted stage,
// dbuf B) + nt loads + LDS-bounced full-line f32 nt C-store.
// Unified 32KB smem: alds=[0,16KB) ; ql=[16KB,32KB) ; later C f32 [32][256].
// ---------------------------------------------------------------------------
__global__ __launch_bounds__(256) void qout_kernel(
    const float* __restrict__ x, const float* __restrict__ xpos,
    const short* __restrict__ wqp, const float* __restrict__ bq,
    const short* __restrict__ ctxT,
    const short* __restrict__ wrp, const float* __restrict__ br,
    float* __restrict__ out)
{
    __shared__ short smem[32 * 512];             // 32KB
    short* alds = smem;                          // [32][256] x-tile / attended
    const int row0 = blockIdx.x * 32;
    const int b = row0 >> 14;
    const int t = threadIdx.x;
    const int w = t >> 6, lane = t & 63;

    { // stage bf16(x+xpos): all loads in flight (nt), then convert
        f32x4 lx[8], lp[8];
        #pragma unroll
        for (int it = 0; it < 8; ++it) {
            int r = it * 4 + w;
            lx[it] = ntld4f(x    + (size_t)(row0 + r) * 256 + lane * 4);
            lp[it] = ntld4f(xpos + (size_t)(row0 + r) * 256 + lane * 4);
        }
        #pragma unroll
        for (int it = 0; it < 8; ++it) {
            int r = it * 4 + w;
            f32x4 a = lx[it] + lp[it];
            s16x4 o;
            o[0]=f2bf(a[0]); o[1]=f2bf(a[1]); o[2]=f2bf(a[2]); o[3]=f2bf(a[3]);
            int swz = ((lane >> 1) ^ (r & 7)) * 8 + (lane & 1) * 4;
            *(s16x4*)(alds + r * 256 + swz) = o;
        }
    }
    __syncthreads();

    const int lrow = lane & 15, lgrp = lane >> 4;
    const int wc = w * 64;
    const int tile0 = wc >> 4;

    float biasq[4];
    #pragma unroll
    for (int nf = 0; nf < 4; ++nf) biasq[nf] = bq[wc + nf * 16 + lrow];

    f32x4 acc[2][4];
    #pragma unroll
    for (int mf = 0; mf < 2; ++mf)
        #pragma unroll
        for (int nf = 0; nf < 4; ++nf) acc[mf][nf] = (f32x4){0.f, 0.f, 0.f, 0.f};

    {   // q-GEMM with double-buffered B
        const short* wq8 = wqp + lane * 8;
        s16x8 bfq[2][4];
        #pragma unroll
        for (int nf = 0; nf < 4; ++nf)
            bfq[0][nf] = *(const s16x8*)(wq8 + ((size_t)(tile0 + nf) * 8 + 0) * 512);
        #pragma unroll
        for (int ks = 0; ks < 8; ++ks) {
            const int cur = ks & 1, nxt = cur ^ 1;
            if (ks < 7) {
                #pragma unroll
                for (int nf = 0; nf < 4; ++nf)
                    bfq[nxt][nf] = *(const s16x8*)(wq8 + ((size_t)(tile0 + nf) * 8 + ks + 1) * 512);
            }
            s16x8 af[2];
            #pragma unroll
            for (int mf = 0; mf < 2; ++mf) {
                int rr = mf * 16 + lrow;
                int cs = (ks * 4 + lgrp) ^ (rr & 7);
                af[mf] = *(const s16x8*)(alds + rr * 256 + cs * 8);
            }
            #pragma unroll
            for (int nf = 0; nf < 4; ++nf) {
                acc[0][nf] = MFMA16(af[0], bfq[cur][nf], acc[0][nf]);
                acc[1][nf] = MFMA16(af[1], bfq[cur][nf], acc[1][nf]);
            }
        }
    }

    // per-head softmax over 32 channels
    short* ql = smem + 8192 + w * 2048;          // [32][64] per wave, swizzled
    #pragma unroll
    for (int mf = 0; mf < 2; ++mf) {
        f32x4 e[4];
        #pragma unroll
        for (int nf = 0; nf < 4; ++nf)
            #pragma unroll
            for (int rr = 0; rr < 4; ++rr)
                e[nf][rr] = __expf(acc[mf][nf][rr] + biasq[nf]);
        #pragma unroll
        for (int hl = 0; hl < 2; ++hl) {
            #pragma unroll
            for (int rr = 0; rr < 4; ++rr) {
                float s = e[hl * 2][rr] + e[hl * 2 + 1][rr];
                s += __shfl_xor(s, 1);
                s += __shfl_xor(s, 2);
                s += __shfl_xor(s, 4);
                s += __shfl_xor(s, 8);
                float rinv = 1.0f / s;
                int row = mf * 16 + lgrp * 4 + rr;
                #pragma unroll
                for (int n2 = 0; n2 < 2; ++n2) {
                    int colc = hl * 32 + n2 * 16 + lrow;
                    int cs = (colc >> 3) ^ (row & 7);
                    ql[row * 64 + cs * 8 + (colc & 7)] = f2bf(e[hl * 2 + n2][rr] * rinv);
                }
            }
        }
    }
    __syncthreads();

    // attend: att[32 x 64] = qsm @ ctx (heads 2w, 2w+1)
    f32x4 att[2][2][2];
    #pragma unroll
    for (int hl = 0; hl < 2; ++hl)
        #pragma unroll
        for (int mf = 0; mf < 2; ++mf)
            #pragma unroll
            for (int n2 = 0; n2 < 2; ++n2) att[hl][mf][n2] = (f32x4){0.f,0.f,0.f,0.f};

    #pragma unroll
    for (int hl = 0; hl < 2; ++hl) {
        const short* cbase = ctxT + (size_t)(b * 8 + w * 2 + hl) * 1024;
        s16x8 bctx[2];
        #pragma unroll
        for (int n2 = 0; n2 < 2; ++n2)
            bctx[n2] = *(const s16x8*)(cbase + (n2 * 16 + lrow) * 32 + lgrp * 8);
        #pragma unroll
        for (int mf = 0; mf < 2; ++mf) {
            int row = mf * 16 + lrow;
            int cs = (hl * 4 + lgrp) ^ (row & 7);
            s16x8 aq = *(const s16x8*)(ql + row * 64 + cs * 8);
            #pragma unroll
            for (int n2 = 0; n2 < 2; ++n2)
                att[hl][mf][n2] = MFMA16(aq, bctx[n2], att[hl][mf][n2]);
        }
    }

    // attended -> alds (bf16, swizzled)
    #pragma unroll
    for (int hl = 0; hl < 2; ++hl)
      #pragma unroll
      for (int mf = 0; mf < 2; ++mf)
        #pragma unroll
        for (int n2 = 0; n2 < 2; ++n2)
          #pragma unroll
          for (int rr = 0; rr < 4; ++rr) {
              int row = mf * 16 + lgrp * 4 + rr;
              int col = wc + hl * 32 + n2 * 16 + lrow;
              int cs = (col >> 3) ^ (row & 7);
              alds[row * 256 + cs * 8 + (col & 7)] = f2bf(att[hl][mf][n2][rr]);
          }
    __syncthreads();

    // reprojection: C = attended @ Wr^T + br  (double-buffered B)
    float biasr[4];
    #pragma unroll
    for (int nf = 0; nf < 4; ++nf) biasr[nf] = br[wc + nf * 16 + lrow];

    f32x4 acc2[2][4];
    #pragma unroll
    for (int mf = 0; mf < 2; ++mf)
        #pragma unroll
        for (int nf = 0; nf < 4; ++nf) acc2[mf][nf] = (f32x4){0.f, 0.f, 0.f, 0.f};

    {
        const short* wr8 = wrp + lane * 8;
        s16x8 bfr[2][4];
        #pragma unroll
        for (int nf = 0; nf < 4; ++nf)
            bfr[0][nf] = *(const s16x8*)(wr8 + ((size_t)(tile0 + nf) * 8 + 0) * 512);
        #pragma unroll
        for (int ks = 0; ks < 8; ++ks) {
            const int cur = ks & 1, nxt = cur ^ 1;
            if (ks < 7) {
                #pragma unroll
                for (int nf = 0; nf < 4; ++nf)
                    bfr[nxt][nf] = *(const s16x8*)(wr8 + ((size_t)(tile0 + nf) * 8 + ks + 1) * 512);
            }
            s16x8 af[2];
            #pragma unroll
            for (int mf = 0; mf < 2; ++mf) {
                int rr = mf * 16 + lrow;
                int cs = (ks * 4 + lgrp) ^ (rr & 7);
                af[mf] = *(const s16x8*)(alds + rr * 256 + cs * 8);
            }
            #pragma unroll
            for (int nf = 0; nf < 4; ++nf) {
                acc2[0][nf] = MFMA16(af[0], bfr[cur][nf], acc2[0][nf]);
                acc2[1][nf] = MFMA16(af[1], bfr[cur][nf], acc2[1][nf]);
            }
        }
    }
    __syncthreads();   // all alds/ql reads done; smem reusable as C f32

    // C -> LDS f32 [32][256], 16B-chunk XOR swizzle; then full-line nt stores
    float* cf = (float*)smem;
    #pragma unroll
    for (int mf = 0; mf < 2; ++mf)
      #pragma unroll
      for (int nf = 0; nf < 4; ++nf)
        #pragma unroll
        for (int rr = 0; rr < 4; ++rr) {
            int row = mf * 16 + lgrp * 4 + rr;
            int col = wc + nf * 16 + lrow;
            int chunk = col >> 2, pos = col & 3;
            cf[row * 256 + ((chunk ^ (row & 7)) << 2) + pos] = acc2[mf][nf][rr] + biasr[nf];
        }
    __syncthreads();

    #pragma unroll
    for (int i = 0; i < 8; ++i) {
        int r = i * 4 + w;
        f32x4 val = *(const f32x4*)(cf + r * 256 + (((lane ^ (r & 7)) & 63) << 2));
        ntst4f(out + (size_t)(row0 + r) * 256 + lane * 4, val);
    }
}

// ---------------------------------------------------------------------------
extern "C" void kernel_launch(void* const* d_in, const int* in_sizes, int n_in,
                              void* d_out, int out_size, void* d_ws, size_t ws_size,
                              hipStream_t stream)
{
    const float* x    = (const float*)d_in[0];
    const float* y    = (const float*)d_in[1];
    const float* xpos = (const float*)d_in[2];
    const float* ypos = (const float*)d_in[3];
    const float* Wq   = (const float*)d_in[4];
    const float* bq   = (const float*)d_in[5];
    const float* Wk   = (const float*)d_in[6];
    const float* bk   = (const float*)d_in[7];
    const float* Wv   = (const float*)d_in[8];
    const float* bv   = (const float*)d_in[9];
    const float* Wr   = (const float*)d_in[10];
    const float* br   = (const float*)d_in[11];

    char*  ws    = (char*)d_ws;
    short* wbf   = (short*)(ws);                    // 512 KB packed weights
    short* ctxT  = (short*)(ws + 524288);           // 64 KB
    float* parts = (float*)(ws + (1 << 20));        // 512*1056 f32 (~2.2 MB)
    short* e_buf = (short*)(ws + ((size_t)4 << 20)); // 33.5 MB
    short* v_buf = e_buf + (size_t)65536 * 256;      // 33.5 MB
    float* outp  = (float*)d_out;

    hipLaunchKernelGGL(wcvt_kernel, dim3(128), dim3(256), 0, stream,
                       Wq, Wk, Wv, Wr, wbf);
    hipLaunchKernelGGL(kv_kernel, dim3(2048), dim3(256), 0, stream,
                       y, ypos, wbf + 65536, wbf + 131072, bk, bv, e_buf, v_buf);
    hipLaunchKernelGGL(ctx_kernel, dim3(16, 32), dim3(256), 0, stream,
                       e_buf, v_buf, parts);
    hipLaunchKernelGGL(ctx_reduce_kernel, dim3(32), dim3(256), 0, stream,
                       parts, ctxT);
    hipLaunchKernelGGL(qout_kernel, dim3(2048), dim3(256), 0, stream,
                       x, xpos, wbf, bq, ctxT, wbf + 196608, br, outp);
}